// Round 4
// baseline (19300.861 us; speedup 1.0000x reference)
//
#include <hip/hip_runtime.h>
#include <hip/hip_cooperative_groups.h>

namespace cg = cooperative_groups;

// TimeVAEDecoder: B=128, LAT=128, H=512, F=128, L=256, NL=2
// Round 7: round-6 + non-temporal streams to protect L2 weight residency.
//  - rocprof r3: 23 MB/step L2-miss @ 358 GB/s. Per-XCD working set was
//    3.9 MB vs 4.0 MB L2 -> cyclic LRU thrash, WAf/WBf refetched every step.
//  - fix: ONLY WAf/WBf use cached loads (3.15 MB/XCD, resident). Everything
//    else streams non-temporally (`nt`, evict-first): WPf/WOf weight loads,
//    GZ*/gb1 bias loads, b_out, and ys output stores. Activations already
//    bypass L2 via sc0 sc1.
//  - everything else identical to round 6 (passed, absmax 0.125):
//    hand-rolled no-invalidate grid barrier, sc0sc1 activation path,
//    rule-#18 sched fences, register cell state, 3-plane split arithmetic.
//  - fallback: per-step launches (round-3 path) if cooperative launch fails.

typedef unsigned int uint32;
typedef unsigned short u16;
typedef __attribute__((ext_vector_type(8))) short bf16x8;
typedef __attribute__((ext_vector_type(4))) float f32x4;

static constexpr int Ln = 256, Fn = 128;
static constexpr int APS = 65536;    // activation plane stride (elems): 128x512
static constexpr int WPS = 2097152;  // cell-weight plane stride: 2048x1024
static constexpr int OPS = 65536;    // W_out plane stride: 128x512
static constexpr int PPS = 262144;   // W_pre plane stride: 512x512

// LDS activation tile: 6 planes (2 sides x 3 split planes) x 16 rows x 520 elems
static constexpr int ROWP = 520;
static constexpr int PLANE = 16 * ROWP;          // 8320 elems
static constexpr int SACT_ELEMS = 6 * PLANE;     // 49920 elems = 99840 B

// lnpre smem union (layout inside the sAct region, byte offsets)
static constexpr int SM_HV   = 0;       // float[16*516] = 33024 B
static constexpr int SM_LNH  = 33024;   // u16[16*520] = 16640 B
static constexpr int SM_LNM  = 49664;
static constexpr int SM_LNL  = 66304;
static constexpr int SM_RED  = 82944;   // float[16][16] = 1024 B
static constexpr int SM_MEAN = 83968;   // float[16]
static constexpr int SM_RSTD = 84032;   // float[16]
static constexpr int SMEM_BYTES = 84096;

__device__ __forceinline__ u16 f2bf(float f) {
  union { float f; uint32 u; } v; v.f = f;
  uint32 u = v.u + 0x7fffu + ((v.u >> 16) & 1u);
  return (u16)(u >> 16);
}
__device__ __forceinline__ float bf2f(u16 h) {
  union { uint32 u; float f; } v; v.u = ((uint32)h) << 16;
  return v.f;
}
__device__ __forceinline__ void splitbf3(float v, u16* hi, u16* mid, u16* lo) {
  u16 h = f2bf(v);
  float r = v - bf2f(h);
  u16 m = f2bf(r);
  float r2 = r - bf2f(m);
  *hi = h; *mid = m; *lo = f2bf(r2);
}
__device__ __forceinline__ float sigm(float x) { return 1.f / (1.f + expf(-x)); }
__device__ __forceinline__ bf16x8 ldf(const u16* p) { return *(const bf16x8*)p; }
// non-temporal (evict-first) loads/stores: stream without thrashing L2
__device__ __forceinline__ bf16x8 ldnt(const u16* p) {
  return __builtin_nontemporal_load((const bf16x8*)p);
}
__device__ __forceinline__ float ldntf(const float* p) {
  return __builtin_nontemporal_load(p);
}
__device__ __forceinline__ void stntf(float* p, float v) {
  __builtin_nontemporal_store(v, p);
}

// device-coherent (L1/L2-bypassing) 16B load / 2B store
__device__ __forceinline__ bf16x8 ldc16(const u16* p) {
  bf16x8 r;
  asm volatile("global_load_dwordx4 %0, %1, off sc0 sc1" : "=v"(r) : "v"(p) : "memory");
  return r;
}
__device__ __forceinline__ void stc2(u16* p, u16 v) {
  asm volatile("global_store_short %0, %1, off sc0 sc1" :: "v"(p), "v"((uint32)v) : "memory");
}
// vmcnt(0) drain + scheduling fence (rule #18: without sched_barrier, hipcc may
// hoist register-only consumers of asm-load results past the waitcnt).
__device__ __forceinline__ void vwait0_fence() {
  asm volatile("s_waitcnt vmcnt(0)" ::: "memory");
  __builtin_amdgcn_sched_barrier(0);
}

// grid barrier WITHOUT cache invalidation: monotonic counter at L3.
__device__ __forceinline__ void gbar(uint32* cnt, uint32 ep) {
  asm volatile("s_waitcnt vmcnt(0) lgkmcnt(0)" ::: "memory");
  __syncthreads();
  if (threadIdx.x == 0) {
    __hip_atomic_fetch_add(cnt, 1u, __ATOMIC_RELAXED, __HIP_MEMORY_SCOPE_AGENT);
    uint32 tgt = ep * 256u;
    while (__hip_atomic_load(cnt, __ATOMIC_RELAXED, __HIP_MEMORY_SCOPE_AGENT) < tgt)
      __builtin_amdgcn_s_sleep(2);
  }
  __syncthreads();
}

#define MFMA1(A, B, ACC) ACC = __builtin_amdgcn_mfma_f32_16x16x32_bf16((A), (B), (ACC), 0, 0, 0)
#define MFMA6(AH, AM, AL, BH, BM, BL, A0, A1, A2) \
  do {                                            \
    MFMA1(AH, BH, A0);                            \
    MFMA1(AH, BM, A1); MFMA1(AM, BH, A1);         \
    MFMA1(AH, BL, A2); MFMA1(AL, BH, A2);         \
    MFMA1(AM, BM, A2);                            \
  } while (0)

// ---------------- persistent-kernel tile functions ----------------

// stage one activation side (3 planes x 16 rows x 512) into sAct[sideBase..]
__device__ __forceinline__ void stage_side(const u16* __restrict__ g, int b0,
                                           u16* sAct, int sideBase, int tid) {
  bf16x8 tv[12];
#pragma unroll
  for (int jr = 0; jr < 12; ++jr) {
    int plane = jr >> 2;
    int c2 = tid + ((jr & 3) << 8);
    int row = c2 >> 6, col = c2 & 63;
    tv[jr] = ldc16(g + (size_t)plane * APS + (size_t)(b0 + row) * 512 + col * 8);
  }
  vwait0_fence();
#pragma unroll
  for (int jr = 0; jr < 12; ++jr) {
    int plane = jr >> 2;
    int c2 = tid + ((jr & 3) << 8);
    int row = c2 >> 6, col = c2 & 63;
    *(bf16x8*)&sAct[sideBase + plane * PLANE + row * ROWP + col * 8] = tv[jr];
  }
}

// LSTM gate tile, persistent version: coherent-staged activations, c in register.
// Weights (WAf/WBf) use CACHED loads -> L2-resident. Bias uses nt loads.
__device__ __forceinline__ void gate_tile_p(
    const u16* __restrict__ g0, const u16* __restrict__ g1,
    const u16* __restrict__ wr,
    const float* __restrict__ bias, int bias_stride,
    float& cr, u16* __restrict__ hout,
    int b0, int h0, int tid, u16* sAct, float (*gbuf)[16][16]) {
  stage_side(g0, b0, sAct, 0, tid);
  stage_side(g1, b0, sAct, 3 * PLANE, tid);
  __syncthreads();
  int lane = tid & 63, w = tid >> 6, q = lane >> 4, r16 = lane & 15;
  const u16* aB = sAct + r16 * ROWP + q * 8;
  f32x4 A0 = {0.f, 0.f, 0.f, 0.f}, A1 = {0.f, 0.f, 0.f, 0.f}, A2 = {0.f, 0.f, 0.f, 0.f};
#pragma unroll
  for (int kb = 0; kb < 16; ++kb) {
    bf16x8 ah = ldf(aB + kb * 32), am = ldf(aB + PLANE + kb * 32), al = ldf(aB + 2 * PLANE + kb * 32);
    bf16x8 bh = ldf(wr + kb * 32), bm = ldf(wr + WPS + kb * 32), bl = ldf(wr + 2 * WPS + kb * 32);
    MFMA6(ah, am, al, bh, bm, bl, A0, A1, A2);
  }
#pragma unroll
  for (int kb = 0; kb < 16; ++kb) {
    bf16x8 ah = ldf(aB + 3 * PLANE + kb * 32), am = ldf(aB + 4 * PLANE + kb * 32),
           al = ldf(aB + 5 * PLANE + kb * 32);
    bf16x8 bh = ldf(wr + 512 + kb * 32), bm = ldf(wr + WPS + 512 + kb * 32),
           bl = ldf(wr + 2 * WPS + 512 + kb * 32);
    MFMA6(ah, am, al, bh, bm, bl, A0, A1, A2);
  }
#pragma unroll
  for (int r = 0; r < 4; ++r)
    gbuf[w][q * 4 + r][r16] = (A2[r] + A1[r]) + A0[r];  // small-to-large
  __syncthreads();
  int bl_ = tid >> 4, hl = tid & 15;
  int b = b0 + bl_, h = h0 + hl;
  const float* bb = bias + (size_t)b * bias_stride;
  float gi = gbuf[0][bl_][hl] + ldntf(bb + h);
  float gf = gbuf[1][bl_][hl] + ldntf(bb + 512 + h);
  float gc = gbuf[2][bl_][hl] + ldntf(bb + 1024 + h);
  float go = gbuf[3][bl_][hl] + ldntf(bb + 1536 + h);
  int idx = b * 512 + h;
  float cn = sigm(gf) * cr + sigm(gi) * tanhf(gc);
  cr = cn;
  float hv_ = sigm(go) * tanhf(cn);
  u16 hh, hm, hl2;
  splitbf3(hv_, &hh, &hm, &hl2);
  stc2(hout + idx, hh);
  stc2(hout + APS + idx, hm);
  stc2(hout + 2 * APS + idx, hl2);
}

// ys output tile, persistent: coherent-staged s, nt weight loads, nt stores.
__device__ __forceinline__ void ys_tile_p(
    const u16* __restrict__ sg, const u16* __restrict__ wr,
    const float* __restrict__ b_out, float* __restrict__ ys,
    int tout, int b0, int f0, int tid, u16* sAct) {
  stage_side(sg, b0, sAct, 0, tid);
  __syncthreads();
  int lane = tid & 63, q = lane >> 4, r16 = lane & 15;
  const u16* aB = sAct + r16 * ROWP + q * 8;
  f32x4 A0 = {0.f, 0.f, 0.f, 0.f}, A1 = {0.f, 0.f, 0.f, 0.f}, A2 = {0.f, 0.f, 0.f, 0.f};
#pragma unroll
  for (int kb = 0; kb < 16; ++kb) {
    bf16x8 ah = ldf(aB + kb * 32), am = ldf(aB + PLANE + kb * 32), al = ldf(aB + 2 * PLANE + kb * 32);
    bf16x8 bh = ldnt(wr + kb * 32), bm = ldnt(wr + OPS + kb * 32), bl = ldnt(wr + 2 * OPS + kb * 32);
    MFMA6(ah, am, al, bh, bm, bl, A0, A1, A2);
  }
  int fc = f0 + r16;
  float bo = ldntf(b_out + fc);
#pragma unroll
  for (int r = 0; r < 4; ++r) {
    int b = b0 + q * 4 + r;
    stntf(&ys[(size_t)b * (Ln * Fn) + (size_t)tout * Fn + fc], ((A2[r] + A1[r]) + A0[r]) + bo);
  }
}

// LN + pre + s', persistent: batched coherent hb loads, nt WPf loads.
__device__ __forceinline__ void lnpre_tile_p(
    const u16* __restrict__ hb, const u16* __restrict__ wr,
    const float* __restrict__ lng, const float* __restrict__ lnb,
    const float* __restrict__ b_pre, u16* __restrict__ s_out,
    int j0, int b0, int tid, char* smem) {
  float* hv = (float*)(smem + SM_HV);
  u16* lnH = (u16*)(smem + SM_LNH);
  u16* lnM = (u16*)(smem + SM_LNM);
  u16* lnL = (u16*)(smem + SM_LNL);
  float (*red)[16] = (float (*)[16])(smem + SM_RED);
  float* smean = (float*)(smem + SM_MEAN);
  float* srstd = (float*)(smem + SM_RSTD);
  bf16x8 p[12];
#pragma unroll
  for (int jj = 0; jj < 4; ++jj) {
    int c = tid + 256 * jj;
    int b = c >> 6, k0 = (c & 63) * 8;
    size_t base = (size_t)(b0 + b) * 512 + k0;
    p[jj * 3 + 0] = ldc16(hb + base);
    p[jj * 3 + 1] = ldc16(hb + APS + base);
    p[jj * 3 + 2] = ldc16(hb + 2 * APS + base);
  }
  vwait0_fence();   // rule #18: fence BEFORE any register-only use of p[]
#pragma unroll
  for (int jj = 0; jj < 4; ++jj) {
    int c = tid + 256 * jj;
    int b = c >> 6, k0 = (c & 63) * 8;
#pragma unroll
    for (int e = 0; e < 8; ++e)
      hv[b * 516 + k0 + e] = (bf2f((u16)p[jj * 3 + 2][e]) + bf2f((u16)p[jj * 3 + 1][e])) +
                             bf2f((u16)p[jj * 3 + 0][e]);
  }
  __syncthreads();
  int bl_ = tid >> 4, kc = tid & 15;
  {  // pass 1: mean
    float sm = 0.f;
    for (int kk = 0; kk < 32; ++kk) sm += hv[bl_ * 516 + kc * 32 + kk];
    red[bl_][kc] = sm;
  }
  __syncthreads();
  if (tid < 16) {
    float s1 = 0.f;
    for (int i = 0; i < 16; ++i) s1 += red[tid][i];
    smean[tid] = s1 * (1.f / 512.f);
  }
  __syncthreads();
  {  // pass 2: variance of deviations
    float m = smean[bl_], sq = 0.f;
    for (int kk = 0; kk < 32; ++kk) {
      float d = hv[bl_ * 516 + kc * 32 + kk] - m;
      sq += d * d;
    }
    red[bl_][kc] = sq;
  }
  __syncthreads();
  if (tid < 16) {
    float s2 = 0.f;
    for (int i = 0; i < 16; ++i) s2 += red[tid][i];
    srstd[tid] = 1.f / sqrtf(s2 * (1.f / 512.f) + 1e-5f);
  }
  __syncthreads();
  for (int i = tid; i < 16 * 512; i += 256) {
    int b = i >> 9, k = i & 511;
    float v = (hv[b * 516 + k] - smean[b]) * srstd[b] * lng[k] + lnb[k];
    splitbf3(v, &lnH[b * 520 + k], &lnM[b * 520 + k], &lnL[b * 520 + k]);
  }
  __syncthreads();
  int lane = tid & 63, w = tid >> 6, q = lane >> 4, r16 = lane & 15;
  const u16* aH = lnH + r16 * 520 + q * 8;
  const u16* aM = lnM + r16 * 520 + q * 8;
  const u16* aL = lnL + r16 * 520 + q * 8;
  f32x4 A0 = {0.f, 0.f, 0.f, 0.f}, A1 = {0.f, 0.f, 0.f, 0.f}, A2 = {0.f, 0.f, 0.f, 0.f};
#pragma unroll
  for (int kb = 0; kb < 16; ++kb) {
    bf16x8 ah = ldf(aH + kb * 32), am = ldf(aM + kb * 32), al = ldf(aL + kb * 32);
    bf16x8 bh = ldnt(wr + kb * 32), bm = ldnt(wr + PPS + kb * 32), bl = ldnt(wr + 2 * PPS + kb * 32);
    MFMA6(ah, am, al, bh, bm, bl, A0, A1, A2);
  }
  int j = j0 + w * 16 + r16;
  float bp = b_pre[j];
#pragma unroll
  for (int r = 0; r < 4; ++r) {
    int b = q * 4 + r;
    float lnv = (hv[b * 516 + j] - smean[b]) * srstd[b] * lng[j] + lnb[j];  // exact fp32 recompute
    float pre = fmaxf(((A2[r] + A1[r]) + A0[r]) + bp, 0.f);
    float sval = pre + lnv;
    size_t sidx = (size_t)(b0 + b) * 512 + j;
    u16 sh, sm_, sl;
    splitbf3(sval, &sh, &sm_, &sl);
    stc2(s_out + sidx, sh);
    stc2(s_out + APS + sidx, sm_);
    stc2(s_out + 2 * APS + sidx, sl);
  }
}

// ---------------- fallback (round-3) tile functions ----------------

__device__ __forceinline__ void gate_tile(
    const u16* __restrict__ a0, const u16* __restrict__ a1,
    const u16* __restrict__ wr,
    const float* __restrict__ bias, int bias_stride,
    float* __restrict__ cstate, u16* __restrict__ hout,
    int b0, int h0, int tid, float (*gbuf)[16][16]) {
  int w = tid >> 6;
  int lane = tid & 63, q = lane >> 4, r16 = lane & 15;
  f32x4 A0 = {0.f, 0.f, 0.f, 0.f}, A1 = {0.f, 0.f, 0.f, 0.f}, A2 = {0.f, 0.f, 0.f, 0.f};
#pragma unroll
  for (int kb = 0; kb < 16; ++kb) {
    bf16x8 ah = ldf(a0 + kb * 32), am = ldf(a0 + APS + kb * 32), al = ldf(a0 + 2 * APS + kb * 32);
    bf16x8 bh = ldf(wr + kb * 32), bm = ldf(wr + WPS + kb * 32), bl = ldf(wr + 2 * WPS + kb * 32);
    MFMA6(ah, am, al, bh, bm, bl, A0, A1, A2);
  }
#pragma unroll
  for (int kb = 0; kb < 16; ++kb) {
    bf16x8 ah = ldf(a1 + kb * 32), am = ldf(a1 + APS + kb * 32), al = ldf(a1 + 2 * APS + kb * 32);
    bf16x8 bh = ldf(wr + 512 + kb * 32), bm = ldf(wr + WPS + 512 + kb * 32),
           bl = ldf(wr + 2 * WPS + 512 + kb * 32);
    MFMA6(ah, am, al, bh, bm, bl, A0, A1, A2);
  }
#pragma unroll
  for (int r = 0; r < 4; ++r)
    gbuf[w][q * 4 + r][r16] = (A2[r] + A1[r]) + A0[r];
  __syncthreads();
  int bl_ = tid >> 4, hl = tid & 15;
  int b = b0 + bl_, h = h0 + hl;
  const float* bb = bias + (size_t)b * bias_stride;
  float gi = gbuf[0][bl_][hl] + bb[h];
  float gf = gbuf[1][bl_][hl] + bb[512 + h];
  float gc = gbuf[2][bl_][hl] + bb[1024 + h];
  float go = gbuf[3][bl_][hl] + bb[1536 + h];
  int idx = b * 512 + h;
  float c = cstate[idx];
  float cn = sigm(gf) * c + sigm(gi) * tanhf(gc);
  cstate[idx] = cn;
  float hv_ = sigm(go) * tanhf(cn);
  splitbf3(hv_, &hout[idx], &hout[APS + idx], &hout[2 * APS + idx]);
  __syncthreads();
}

__device__ __forceinline__ void ys_tile(
    const u16* __restrict__ a, const u16* __restrict__ wr,
    const float* __restrict__ b_out, float* __restrict__ ys,
    int tout, int b0, int f0, int tid) {
  int lane = tid & 63, q = lane >> 4, r16 = lane & 15;
  f32x4 A0 = {0.f, 0.f, 0.f, 0.f}, A1 = {0.f, 0.f, 0.f, 0.f}, A2 = {0.f, 0.f, 0.f, 0.f};
#pragma unroll
  for (int kb = 0; kb < 16; ++kb) {
    bf16x8 ah = ldf(a + kb * 32), am = ldf(a + APS + kb * 32), al = ldf(a + 2 * APS + kb * 32);
    bf16x8 bh = ldf(wr + kb * 32), bm = ldf(wr + OPS + kb * 32), bl = ldf(wr + 2 * OPS + kb * 32);
    MFMA6(ah, am, al, bh, bm, bl, A0, A1, A2);
  }
  int fc = f0 + r16;
  float bo = b_out[fc];
#pragma unroll
  for (int r = 0; r < 4; ++r) {
    int b = b0 + q * 4 + r;
    ys[(size_t)b * (Ln * Fn) + (size_t)tout * Fn + fc] = ((A2[r] + A1[r]) + A0[r]) + bo;
  }
}

__device__ __forceinline__ void lnpre_tile(
    const u16* __restrict__ hb, const u16* __restrict__ wr,
    const float* __restrict__ lng, const float* __restrict__ lnb,
    const float* __restrict__ b_pre, u16* __restrict__ s_out,
    int j0, int b0, int tid, char* smem) {
  float* hv = (float*)(smem + SM_HV);
  u16* lnH = (u16*)(smem + SM_LNH);
  u16* lnM = (u16*)(smem + SM_LNM);
  u16* lnL = (u16*)(smem + SM_LNL);
  float (*red)[16] = (float (*)[16])(smem + SM_RED);
  float* smean = (float*)(smem + SM_MEAN);
  float* srstd = (float*)(smem + SM_RSTD);
  for (int i = tid; i < 16 * 512; i += 256) {
    int b = i >> 9, k = i & 511;
    size_t hidx = (size_t)(b0 + b) * 512 + k;
    hv[b * 516 + k] = (bf2f(hb[2 * APS + hidx]) + bf2f(hb[APS + hidx])) + bf2f(hb[hidx]);
  }
  __syncthreads();
  int bl_ = tid >> 4, kc = tid & 15;
  {
    float sm = 0.f;
    for (int kk = 0; kk < 32; ++kk) sm += hv[bl_ * 516 + kc * 32 + kk];
    red[bl_][kc] = sm;
  }
  __syncthreads();
  if (tid < 16) {
    float s1 = 0.f;
    for (int i = 0; i < 16; ++i) s1 += red[tid][i];
    smean[tid] = s1 * (1.f / 512.f);
  }
  __syncthreads();
  {
    float m = smean[bl_], sq = 0.f;
    for (int kk = 0; kk < 32; ++kk) {
      float d = hv[bl_ * 516 + kc * 32 + kk] - m;
      sq += d * d;
    }
    red[bl_][kc] = sq;
  }
  __syncthreads();
  if (tid < 16) {
    float s2 = 0.f;
    for (int i = 0; i < 16; ++i) s2 += red[tid][i];
    srstd[tid] = 1.f / sqrtf(s2 * (1.f / 512.f) + 1e-5f);
  }
  __syncthreads();
  for (int i = tid; i < 16 * 512; i += 256) {
    int b = i >> 9, k = i & 511;
    float v = (hv[b * 516 + k] - smean[b]) * srstd[b] * lng[k] + lnb[k];
    splitbf3(v, &lnH[b * 520 + k], &lnM[b * 520 + k], &lnL[b * 520 + k]);
  }
  __syncthreads();
  int lane = tid & 63, w = tid >> 6, q = lane >> 4, r16 = lane & 15;
  const u16* aH = lnH + r16 * 520 + q * 8;
  const u16* aM = lnM + r16 * 520 + q * 8;
  const u16* aL = lnL + r16 * 520 + q * 8;
  f32x4 A0 = {0.f, 0.f, 0.f, 0.f}, A1 = {0.f, 0.f, 0.f, 0.f}, A2 = {0.f, 0.f, 0.f, 0.f};
#pragma unroll
  for (int kb = 0; kb < 16; ++kb) {
    bf16x8 ah = ldf(aH + kb * 32), am = ldf(aM + kb * 32), al = ldf(aL + kb * 32);
    bf16x8 bh = ldf(wr + kb * 32), bm = ldf(wr + PPS + kb * 32), bl = ldf(wr + 2 * PPS + kb * 32);
    MFMA6(ah, am, al, bh, bm, bl, A0, A1, A2);
  }
  int j = j0 + w * 16 + r16;
  float bp = b_pre[j];
#pragma unroll
  for (int r = 0; r < 4; ++r) {
    int b = q * 4 + r;
    float lnv = (hv[b * 516 + j] - smean[b]) * srstd[b] * lng[j] + lnb[j];
    float pre = fmaxf(((A2[r] + A1[r]) + A0[r]) + bp, 0.f);
    float sval = pre + lnv;
    size_t sidx = (size_t)(b0 + b) * 512 + j;
    splitbf3(sval, &s_out[sidx], &s_out[APS + sidx], &s_out[2 * APS + sidx]);
  }
  __syncthreads();
}

// ---------------- prep kernels ----------------

__global__ void prep_hc0(const float* __restrict__ z,
                         const float* __restrict__ W_l2h, const float* __restrict__ b_l2h,
                         const float* __restrict__ W_l2c, const float* __restrict__ b_l2c,
                         u16* __restrict__ ha0, u16* __restrict__ hb0,
                         float* __restrict__ ca, float* __restrict__ cb) {
  int idx = blockIdx.x * 256 + threadIdx.x;  // 131072
  int b = idx & 127, j = idx >> 7;
  float ah = b_l2h[j], ac = b_l2c[j];
  for (int k = 0; k < 128; ++k) {
    float zv = z[b * 128 + k];
    ah += zv * W_l2h[j * 128 + k];
    ac += zv * W_l2c[j * 128 + k];
  }
  int flat = b * 1024 + j;
  if (flat < 65536) {
    splitbf3(ah, &ha0[flat], &ha0[APS + flat], &ha0[2 * APS + flat]);
    ca[flat] = ac;
  } else {
    flat -= 65536;
    splitbf3(ah, &hb0[flat], &hb0[APS + flat], &hb0[2 * APS + flat]);
    cb[flat] = ac;
  }
}

__global__ void prep_zp(const float* __restrict__ z, const float* __restrict__ W_zp,
                        const float* __restrict__ b_zp, float* __restrict__ zp) {
  int idx = blockIdx.x * 256 + threadIdx.x;  // 65536
  int b = idx & 127, h = idx >> 7;
  float a = b_zp[h];
  for (int k = 0; k < 128; ++k) a += z[b * 128 + k] * W_zp[h * 128 + k];
  zp[b * 512 + h] = a;
}

__global__ void prep_gz(const float* __restrict__ zp, const float* __restrict__ W_ih0,
                        const float* __restrict__ b_ih0, const float* __restrict__ b_hh0,
                        const float* __restrict__ b_out,
                        float* __restrict__ GZ0, float* __restrict__ GZ1) {
  int idx = blockIdx.x * 256 + threadIdx.x;  // 262144
  int b = idx & 127, g = idx >> 7;
  const float* wr = W_ih0 + (size_t)g * 640;
  float a = b_ih0[g] + b_hh0[g];
  for (int k = 0; k < 512; ++k) a += zp[b * 512 + k] * wr[128 + k];
  float co = 0.f;
  for (int f = 0; f < 128; ++f) co += b_out[f] * wr[f];
  GZ0[b * 2048 + g] = a;
  GZ1[b * 2048 + g] = a + co;
}

__global__ void prep_waf(const float* __restrict__ W_out, const float* __restrict__ W_ih0,
                         const float* __restrict__ W_hh0, u16* __restrict__ WAf) {
  int idx = blockIdx.x * 256 + threadIdx.x;  // 2097152
  int k = idx & 1023, g = idx >> 10;
  float v;
  if (k < 512) {
    v = 0.f;
    const float* wr = W_ih0 + (size_t)g * 640;
    for (int f = 0; f < 128; ++f) v += W_out[f * 512 + k] * wr[f];
  } else {
    v = W_hh0[(size_t)g * 512 + (k - 512)];
  }
  splitbf3(v, &WAf[idx], &WAf[WPS + idx], &WAf[2 * WPS + idx]);
}

__global__ void prep_wbf(const float* __restrict__ W_ih1, const float* __restrict__ W_hh1,
                         u16* __restrict__ WBf) {
  int idx = blockIdx.x * 256 + threadIdx.x;  // 2097152
  int k = idx & 1023, g = idx >> 10;
  float v = (k < 512) ? W_ih1[(size_t)g * 512 + k] : W_hh1[(size_t)g * 512 + (k - 512)];
  splitbf3(v, &WBf[idx], &WBf[WPS + idx], &WBf[2 * WPS + idx]);
}

__global__ void prep_misc(const float* __restrict__ W_pre, const float* __restrict__ W_out,
                          const float* __restrict__ b_ih1, const float* __restrict__ b_hh1,
                          u16* __restrict__ WPf, u16* __restrict__ WOf,
                          float* __restrict__ gb1, u16* __restrict__ s,
                          uint32* __restrict__ bar) {
  int idx = blockIdx.x * 256 + threadIdx.x;  // 526400 total
  if (idx < 262144) { splitbf3(W_pre[idx], &WPf[idx], &WPf[PPS + idx], &WPf[2 * PPS + idx]); return; }
  idx -= 262144;
  if (idx < 65536) { splitbf3(W_out[idx], &WOf[idx], &WOf[OPS + idx], &WOf[2 * OPS + idx]); return; }
  idx -= 65536;
  if (idx < 2048) { gb1[idx] = b_ih1[idx] + b_hh1[idx]; return; }
  idx -= 2048;
  if (idx < 196608) { s[idx] = 0; return; }  // all 3 planes of s1: dec(0)=0 via GZ0
  idx -= 196608;
  if (idx < 64) bar[idx] = 0;                // barrier counter
}

// ---------------- persistent kernel ----------------

__global__ __launch_bounds__(256, 1) void loop_k(
    const u16* __restrict__ WAf, const u16* __restrict__ WBf,
    const u16* __restrict__ WPf, const u16* __restrict__ WOf,
    const float* __restrict__ GZ0, const float* __restrict__ GZ1,
    const float* __restrict__ gb1,
    const float* __restrict__ ca, const float* __restrict__ cb,
    u16* __restrict__ ha0, u16* __restrict__ ha1,
    u16* __restrict__ hb0, u16* __restrict__ hb1,
    u16* __restrict__ s0, u16* __restrict__ s1,
    const float* __restrict__ lng, const float* __restrict__ lnb,
    const float* __restrict__ b_pre, const float* __restrict__ b_out,
    float* __restrict__ ys, uint32* __restrict__ bar) {
  __shared__ __align__(16) u16 sAct[SACT_ELEMS];   // 99840 B, aliased by lnpre union
  __shared__ float gbuf[4][16][16];                // 4096 B, separate
  int tid = threadIdx.x;
  int lane = tid & 63, w = tid >> 6, q = lane >> 4, r16 = lane & 15;
  int blk = blockIdx.x;

  int gg = blk & 31, bg = blk >> 5;
  int h0A = gg * 16, b0A = bg * 16;
  size_t wro = (size_t)(w * 512 + h0A + r16) * 1024 + q * 8;
  const u16* wrA = WAf + wro;
  const u16* wrB = WBf + wro;

  int jg = blk & 7, bgC = blk >> 3;
  int j0 = jg * 64, b0C = bgC * 16;
  const u16* wrP = WPf + (size_t)(j0 + w * 16 + r16) * 512 + q * 8;

  int ob = (blk - 64) & 15;
  int bgY = ob >> 1, fh = ob & 1;
  int b0Y = bgY * 16, f0 = fh * 64 + w * 16;
  const u16* wrO = WOf + (size_t)(f0 + r16) * 512 + q * 8;

  // cell state in registers: this thread owns (b0A+tid>>4, h0A+tid&15) forever
  int cidx = (b0A + (tid >> 4)) * 512 + h0A + (tid & 15);
  float cA = ca[cidx], cB = cb[cidx];

  uint32 ep = 0;
  for (int t = 0; t < Ln; ++t) {
    u16* sPrev = (t & 1) ? s0 : s1;   // written by phase C of t-1 (s1 zeroed for t=0)
    u16* sNext = (t & 1) ? s1 : s0;
    u16* haIn  = (t & 1) ? ha1 : ha0;
    u16* haOut = (t & 1) ? ha0 : ha1;
    u16* hbIn  = (t & 1) ? hb1 : hb0;
    u16* hbOut = (t & 1) ? hb0 : hb1;

    // phase A: cell0 (K=1024: s || ha)
    gate_tile_p(sPrev, haIn, wrA, t ? GZ1 : GZ0, 2048, cA, haOut, b0A, h0A, tid, sAct, gbuf);
    gbar(bar, ++ep);
    // phase B: cell1 (K=1024: ha' || hb)
    gate_tile_p(haOut, hbIn, wrB, gb1, 0, cB, hbOut, b0A, h0A, tid, sAct, gbuf);
    gbar(bar, ++ep);
    // phase C: lnpre (blocks 0..63) || ys[t-1] (blocks 64..79)
    if (blk < 64) {
      lnpre_tile_p(hbOut, wrP, lng, lnb, b_pre, sNext, j0, b0C, tid, (char*)sAct);
    } else if (blk < 80 && t > 0) {
      ys_tile_p(sPrev, wrO, b_out, ys, t - 1, b0Y, f0, tid, sAct);
    }
    gbar(bar, ++ep);
  }
  // epilogue: ys[L-1] from final s (t=255 wrote s1)
  if (blk >= 64 && blk < 80) {
    ys_tile_p(s1, wrO, b_out, ys, Ln - 1, b0Y, f0, tid, sAct);
  }
}

// ---------------- fallback per-step kernels (round-3 path) ----------------

__global__ void cell_k(const u16* __restrict__ x0, const u16* __restrict__ x1,
                       const u16* __restrict__ Wf,
                       const float* __restrict__ bias, int bias_stride,
                       float* __restrict__ cstate, u16* __restrict__ hout,
                       int n_gate_blocks,
                       const u16* sv, const u16* __restrict__ WOf,
                       const float* __restrict__ b_out, float* __restrict__ ys, int t) {
  __shared__ float gbuf[4][16][16];
  int tid = threadIdx.x;
  int lane = tid & 63, w = tid >> 6, q = lane >> 4, r16 = lane & 15;
  int blk = blockIdx.x;
  if (blk < n_gate_blocks) {
    int gg = blk & 31, bg = blk >> 5;
    int h0 = gg * 16, b0 = bg * 16;
    const u16* wr = Wf + (size_t)(w * 512 + h0 + r16) * 1024 + q * 8;
    size_t aoff = (size_t)(b0 + r16) * 512 + q * 8;
    gate_tile(x0 + aoff, x1 + aoff, wr, bias, bias_stride, cstate, hout, b0, h0, tid, gbuf);
  } else {
    if (t < 1) return;
    int ob = blk - n_gate_blocks;
    int bg = ob >> 1, fh = ob & 1;
    int b0 = bg * 16, f0 = fh * 64 + w * 16;
    const u16* wr = WOf + (size_t)(f0 + r16) * 512 + q * 8;
    size_t aoff = (size_t)(b0 + r16) * 512 + q * 8;
    ys_tile(sv + aoff, wr, b_out, ys, t - 1, b0, f0, tid);
  }
}

__global__ void lnpre_k(const u16* __restrict__ hb, const u16* __restrict__ WPf,
                        const float* __restrict__ lng, const float* __restrict__ lnb,
                        const float* __restrict__ b_pre, u16* __restrict__ s_out) {
  __shared__ __align__(16) char smem[SMEM_BYTES];
  int tid = threadIdx.x;
  int lane = tid & 63, w = tid >> 6, q = lane >> 4, r16 = lane & 15;
  int jg = blockIdx.x & 7, bg = blockIdx.x >> 3;
  int j0 = jg * 64, b0 = bg * 16;
  const u16* wr = WPf + (size_t)(j0 + w * 16 + r16) * 512 + q * 8;
  lnpre_tile(hb, wr, lng, lnb, b_pre, s_out, j0, b0, tid, smem);
}

// ---------------- host ----------------

extern "C" void kernel_launch(void* const* d_in, const int* in_sizes, int n_in,
                              void* d_out, int out_size, void* d_ws, size_t ws_size,
                              hipStream_t stream) {
  const float* z     = (const float*)d_in[0];
  const float* W_l2h = (const float*)d_in[1];
  const float* b_l2h = (const float*)d_in[2];
  const float* W_l2c = (const float*)d_in[3];
  const float* b_l2c = (const float*)d_in[4];
  const float* W_zp  = (const float*)d_in[5];
  const float* b_zp  = (const float*)d_in[6];
  const float* W_ih0 = (const float*)d_in[7];
  const float* W_hh0 = (const float*)d_in[8];
  const float* b_ih0 = (const float*)d_in[9];
  const float* b_hh0 = (const float*)d_in[10];
  const float* W_ih1 = (const float*)d_in[11];
  const float* W_hh1 = (const float*)d_in[12];
  const float* b_ih1 = (const float*)d_in[13];
  const float* b_hh1 = (const float*)d_in[14];
  const float* ln_g  = (const float*)d_in[15];
  const float* ln_b  = (const float*)d_in[16];
  const float* W_pre = (const float*)d_in[17];
  const float* b_pre = (const float*)d_in[18];
  const float* W_out = (const float*)d_in[19];
  const float* b_out = (const float*)d_in[20];
  float* out = (float*)d_out;
  char* ws = (char*)d_ws;

  size_t off = 0;
  auto alloc = [&](size_t bytes) { void* p = ws + off; off += bytes; return p; };
  u16*   WAf  = (u16*)alloc(12582912);   // 3 planes x 2048x1024 bf16
  u16*   WBf  = (u16*)alloc(12582912);
  u16*   WPf  = (u16*)alloc(1572864);    // 3 x 512x512
  u16*   WOf  = (u16*)alloc(393216);     // 3 x 128x512
  float* GZ0  = (float*)alloc(1048576);
  float* GZ1  = (float*)alloc(1048576);
  float* gb1  = (float*)alloc(8192);
  float* zp   = (float*)alloc(262144);
  u16*   ha[2], *hbuf[2], *sb[2];
  ha[0]   = (u16*)alloc(393216);         // 3 planes x 128x512
  ha[1]   = (u16*)alloc(393216);
  hbuf[0] = (u16*)alloc(393216);
  hbuf[1] = (u16*)alloc(393216);
  float* ca   = (float*)alloc(262144);
  float* cb   = (float*)alloc(262144);
  sb[0]   = (u16*)alloc(393216);
  sb[1]   = (u16*)alloc(393216);
  uint32* bar = (uint32*)alloc(256);

  prep_hc0<<<512, 256, 0, stream>>>(z, W_l2h, b_l2h, W_l2c, b_l2c, ha[0], hbuf[0], ca, cb);
  prep_zp<<<256, 256, 0, stream>>>(z, W_zp, b_zp, zp);
  prep_gz<<<1024, 256, 0, stream>>>(zp, W_ih0, b_ih0, b_hh0, b_out, GZ0, GZ1);
  prep_waf<<<8192, 256, 0, stream>>>(W_out, W_ih0, W_hh0, WAf);
  prep_wbf<<<8192, 256, 0, stream>>>(W_ih1, W_hh1, WBf);
  prep_misc<<<2057, 256, 0, stream>>>(W_pre, W_out, b_ih1, b_hh1, WPf, WOf, gb1, sb[1], bar);

  static int coop_supported = -1;
  if (coop_supported < 0) {
    int dev = 0;
    (void)hipGetDevice(&dev);
    int v = 0;
    (void)hipDeviceGetAttribute(&v, hipDeviceAttributeCooperativeLaunch, dev);
    coop_supported = v;
  }

  bool did_coop = false;
  if (coop_supported) {
    void* kargs[] = {
        (void*)&WAf, (void*)&WBf, (void*)&WPf, (void*)&WOf,
        (void*)&GZ0, (void*)&GZ1, (void*)&gb1, (void*)&ca, (void*)&cb,
        (void*)&ha[0], (void*)&ha[1], (void*)&hbuf[0], (void*)&hbuf[1],
        (void*)&sb[0], (void*)&sb[1],
        (void*)&ln_g, (void*)&ln_b, (void*)&b_pre, (void*)&b_out, (void*)&out,
        (void*)&bar};
    hipError_t err = hipLaunchCooperativeKernel((const void*)loop_k, dim3(256), dim3(256),
                                                kargs, 0, stream);
    did_coop = (err == hipSuccess);
  }

  if (!did_coop) {
    // fallback: per-step launches (round-3 structure)
    for (int t = 0; t < Ln; ++t) {
      u16* sPrev = (t & 1) ? sb[0] : sb[1];
      u16* sNext = (t & 1) ? sb[1] : sb[0];
      u16* haIn = ha[t & 1];
      u16* haOut = ha[(t + 1) & 1];
      u16* hbIn = hbuf[t & 1];
      u16* hbOut = hbuf[(t + 1) & 1];
      cell_k<<<272, 256, 0, stream>>>(sPrev, haIn, WAf, t ? GZ1 : GZ0, 2048,
                                      ca, haOut, 256, sPrev, WOf, b_out, out, t);
      cell_k<<<256, 256, 0, stream>>>(haOut, hbIn, WBf, gb1, 0,
                                      cb, hbOut, 256, sPrev, WOf, b_out, out, 0);
      lnpre_k<<<64, 256, 0, stream>>>(hbOut, WPf, ln_g, ln_b, b_pre, sNext);
    }
    cell_k<<<16, 256, 0, stream>>>(sb[1], ha[0], WAf, GZ1, 2048, ca, ha[1],
                                   0, sb[1], WOf, b_out, out, Ln);
  }
}

// Round 5
// 14311.937 us; speedup vs baseline: 1.3486x; 1.3486x over previous
//
#include <hip/hip_runtime.h>
#include <hip/hip_cooperative_groups.h>

namespace cg = cooperative_groups;

// TimeVAEDecoder: B=128, LAT=128, H=512, F=128, L=256, NL=2
// Round 8: round-6 (=16.8ms, passed) + contention-free flag barrier; nt reverted.
//  - rocprof r4: MfmaUtil 3.7%, VALU 3.3%, HBM 3.8% -> ~95% idle. Barrier
//    analysis: 256 same-line atomic RMWs serialize at ~L3 latency each ->
//    O(15+ us)/barrier x 768 barriers ~= the whole runtime.
//  - new gbar: per-block 64B-spaced arrival slots (plain agent stores, zero
//    contention); block 0 scans all slots in parallel (1 slot/thread +
//    __syncthreads_and) and publishes a release epoch; others poll one word.
//    No atomics at all.
//  - nt hints of round 7 reverted (FETCH unchanged, perf regressed): cached
//    weight loads as in round 6.
//  - everything else bit-identical to round 6: sc0sc1 activation path through
//    L3, rule-#18 sched fences, register cell state, 3-plane split arithmetic.
//  - fallback: per-step launches (round-3 path) if cooperative launch fails.

typedef unsigned int uint32;
typedef unsigned short u16;
typedef __attribute__((ext_vector_type(8))) short bf16x8;
typedef __attribute__((ext_vector_type(4))) float f32x4;

static constexpr int Ln = 256, Fn = 128;
static constexpr int APS = 65536;    // activation plane stride (elems): 128x512
static constexpr int WPS = 2097152;  // cell-weight plane stride: 2048x1024
static constexpr int OPS = 65536;    // W_out plane stride: 128x512
static constexpr int PPS = 262144;   // W_pre plane stride: 512x512

// barrier region: 256 arrival slots (64B-spaced uint32) + release word
static constexpr int BAR_REL = 4096;    // arr[0..4095], rel at [4096]
static constexpr int BAR_WORDS = 4160;

// LDS activation tile: 6 planes (2 sides x 3 split planes) x 16 rows x 520 elems
static constexpr int ROWP = 520;
static constexpr int PLANE = 16 * ROWP;          // 8320 elems
static constexpr int SACT_ELEMS = 6 * PLANE;     // 49920 elems = 99840 B

// lnpre smem union (layout inside the sAct region, byte offsets)
static constexpr int SM_HV   = 0;       // float[16*516] = 33024 B
static constexpr int SM_LNH  = 33024;   // u16[16*520] = 16640 B
static constexpr int SM_LNM  = 49664;
static constexpr int SM_LNL  = 66304;
static constexpr int SM_RED  = 82944;   // float[16][16] = 1024 B
static constexpr int SM_MEAN = 83968;   // float[16]
static constexpr int SM_RSTD = 84032;   // float[16]
static constexpr int SMEM_BYTES = 84096;

__device__ __forceinline__ u16 f2bf(float f) {
  union { float f; uint32 u; } v; v.f = f;
  uint32 u = v.u + 0x7fffu + ((v.u >> 16) & 1u);
  return (u16)(u >> 16);
}
__device__ __forceinline__ float bf2f(u16 h) {
  union { uint32 u; float f; } v; v.u = ((uint32)h) << 16;
  return v.f;
}
__device__ __forceinline__ void splitbf3(float v, u16* hi, u16* mid, u16* lo) {
  u16 h = f2bf(v);
  float r = v - bf2f(h);
  u16 m = f2bf(r);
  float r2 = r - bf2f(m);
  *hi = h; *mid = m; *lo = f2bf(r2);
}
__device__ __forceinline__ float sigm(float x) { return 1.f / (1.f + expf(-x)); }
__device__ __forceinline__ bf16x8 ldf(const u16* p) { return *(const bf16x8*)p; }

// device-coherent (L1/L2-bypassing) 16B load / 2B store
__device__ __forceinline__ bf16x8 ldc16(const u16* p) {
  bf16x8 r;
  asm volatile("global_load_dwordx4 %0, %1, off sc0 sc1" : "=v"(r) : "v"(p) : "memory");
  return r;
}
__device__ __forceinline__ void stc2(u16* p, u16 v) {
  asm volatile("global_store_short %0, %1, off sc0 sc1" :: "v"(p), "v"((uint32)v) : "memory");
}
// vmcnt(0) drain + scheduling fence (rule #18)
__device__ __forceinline__ void vwait0_fence() {
  asm volatile("s_waitcnt vmcnt(0)" ::: "memory");
  __builtin_amdgcn_sched_barrier(0);
}

// Contention-free grid barrier: per-block arrival slots + scanner + release word.
// No atomics. Monotonic epochs; slots zeroed by prep_misc each launch/replay.
__device__ __forceinline__ void gbar(uint32* arr, uint32* rel, uint32 ep, int blk) {
  asm volatile("s_waitcnt vmcnt(0) lgkmcnt(0)" ::: "memory");
  __syncthreads();
  int tid = threadIdx.x;
  if (blk == 0) {
    // scanner: each thread owns one arrival slot (slot 0 = ourselves, skip)
    for (;;) {
      uint32 v = __hip_atomic_load(&arr[tid * 16], __ATOMIC_RELAXED, __HIP_MEMORY_SCOPE_AGENT);
      if (__syncthreads_and((tid == 0) || (v >= ep))) break;
      __builtin_amdgcn_s_sleep(1);
    }
    if (tid == 0)
      __hip_atomic_store(rel, ep, __ATOMIC_RELAXED, __HIP_MEMORY_SCOPE_AGENT);
  } else {
    if (tid == 0) {
      __hip_atomic_store(&arr[blk * 16], ep, __ATOMIC_RELAXED, __HIP_MEMORY_SCOPE_AGENT);
      while (__hip_atomic_load(rel, __ATOMIC_RELAXED, __HIP_MEMORY_SCOPE_AGENT) < ep)
        __builtin_amdgcn_s_sleep(1);
    }
  }
  __syncthreads();
  __builtin_amdgcn_sched_barrier(0);
}

#define MFMA1(A, B, ACC) ACC = __builtin_amdgcn_mfma_f32_16x16x32_bf16((A), (B), (ACC), 0, 0, 0)
#define MFMA6(AH, AM, AL, BH, BM, BL, A0, A1, A2) \
  do {                                            \
    MFMA1(AH, BH, A0);                            \
    MFMA1(AH, BM, A1); MFMA1(AM, BH, A1);         \
    MFMA1(AH, BL, A2); MFMA1(AL, BH, A2);         \
    MFMA1(AM, BM, A2);                            \
  } while (0)

// ---------------- persistent-kernel tile functions ----------------

// stage one activation side (3 planes x 16 rows x 512) into sAct[sideBase..]
__device__ __forceinline__ void stage_side(const u16* __restrict__ g, int b0,
                                           u16* sAct, int sideBase, int tid) {
  bf16x8 tv[12];
#pragma unroll
  for (int jr = 0; jr < 12; ++jr) {
    int plane = jr >> 2;
    int c2 = tid + ((jr & 3) << 8);
    int row = c2 >> 6, col = c2 & 63;
    tv[jr] = ldc16(g + (size_t)plane * APS + (size_t)(b0 + row) * 512 + col * 8);
  }
  vwait0_fence();
#pragma unroll
  for (int jr = 0; jr < 12; ++jr) {
    int plane = jr >> 2;
    int c2 = tid + ((jr & 3) << 8);
    int row = c2 >> 6, col = c2 & 63;
    *(bf16x8*)&sAct[sideBase + plane * PLANE + row * ROWP + col * 8] = tv[jr];
  }
}

// LSTM gate tile, persistent version: coherent-staged activations, c in register.
__device__ __forceinline__ void gate_tile_p(
    const u16* __restrict__ g0, const u16* __restrict__ g1,
    const u16* __restrict__ wr,
    const float* __restrict__ bias, int bias_stride,
    float& cr, u16* __restrict__ hout,
    int b0, int h0, int tid, u16* sAct, float (*gbuf)[16][16]) {
  stage_side(g0, b0, sAct, 0, tid);
  stage_side(g1, b0, sAct, 3 * PLANE, tid);
  __syncthreads();
  int lane = tid & 63, w = tid >> 6, q = lane >> 4, r16 = lane & 15;
  const u16* aB = sAct + r16 * ROWP + q * 8;
  f32x4 A0 = {0.f, 0.f, 0.f, 0.f}, A1 = {0.f, 0.f, 0.f, 0.f}, A2 = {0.f, 0.f, 0.f, 0.f};
#pragma unroll
  for (int kb = 0; kb < 16; ++kb) {
    bf16x8 ah = ldf(aB + kb * 32), am = ldf(aB + PLANE + kb * 32), al = ldf(aB + 2 * PLANE + kb * 32);
    bf16x8 bh = ldf(wr + kb * 32), bm = ldf(wr + WPS + kb * 32), bl = ldf(wr + 2 * WPS + kb * 32);
    MFMA6(ah, am, al, bh, bm, bl, A0, A1, A2);
  }
#pragma unroll
  for (int kb = 0; kb < 16; ++kb) {
    bf16x8 ah = ldf(aB + 3 * PLANE + kb * 32), am = ldf(aB + 4 * PLANE + kb * 32),
           al = ldf(aB + 5 * PLANE + kb * 32);
    bf16x8 bh = ldf(wr + 512 + kb * 32), bm = ldf(wr + WPS + 512 + kb * 32),
           bl = ldf(wr + 2 * WPS + 512 + kb * 32);
    MFMA6(ah, am, al, bh, bm, bl, A0, A1, A2);
  }
#pragma unroll
  for (int r = 0; r < 4; ++r)
    gbuf[w][q * 4 + r][r16] = (A2[r] + A1[r]) + A0[r];  // small-to-large
  __syncthreads();
  int bl_ = tid >> 4, hl = tid & 15;
  int b = b0 + bl_, h = h0 + hl;
  const float* bb = bias + (size_t)b * bias_stride;
  float gi = gbuf[0][bl_][hl] + bb[h];
  float gf = gbuf[1][bl_][hl] + bb[512 + h];
  float gc = gbuf[2][bl_][hl] + bb[1024 + h];
  float go = gbuf[3][bl_][hl] + bb[1536 + h];
  int idx = b * 512 + h;
  float cn = sigm(gf) * cr + sigm(gi) * tanhf(gc);
  cr = cn;
  float hv_ = sigm(go) * tanhf(cn);
  u16 hh, hm, hl2;
  splitbf3(hv_, &hh, &hm, &hl2);
  stc2(hout + idx, hh);
  stc2(hout + APS + idx, hm);
  stc2(hout + 2 * APS + idx, hl2);
}

// ys output tile, persistent: coherent-staged s, LDS MFMA reads.
__device__ __forceinline__ void ys_tile_p(
    const u16* __restrict__ sg, const u16* __restrict__ wr,
    const float* __restrict__ b_out, float* __restrict__ ys,
    int tout, int b0, int f0, int tid, u16* sAct) {
  stage_side(sg, b0, sAct, 0, tid);
  __syncthreads();
  int lane = tid & 63, q = lane >> 4, r16 = lane & 15;
  const u16* aB = sAct + r16 * ROWP + q * 8;
  f32x4 A0 = {0.f, 0.f, 0.f, 0.f}, A1 = {0.f, 0.f, 0.f, 0.f}, A2 = {0.f, 0.f, 0.f, 0.f};
#pragma unroll
  for (int kb = 0; kb < 16; ++kb) {
    bf16x8 ah = ldf(aB + kb * 32), am = ldf(aB + PLANE + kb * 32), al = ldf(aB + 2 * PLANE + kb * 32);
    bf16x8 bh = ldf(wr + kb * 32), bm = ldf(wr + OPS + kb * 32), bl = ldf(wr + 2 * OPS + kb * 32);
    MFMA6(ah, am, al, bh, bm, bl, A0, A1, A2);
  }
  int fc = f0 + r16;
  float bo = b_out[fc];
#pragma unroll
  for (int r = 0; r < 4; ++r) {
    int b = b0 + q * 4 + r;
    ys[(size_t)b * (Ln * Fn) + (size_t)tout * Fn + fc] = ((A2[r] + A1[r]) + A0[r]) + bo;
  }
}

// LN + pre + s', persistent: batched coherent hb loads (single wait+fence).
__device__ __forceinline__ void lnpre_tile_p(
    const u16* __restrict__ hb, const u16* __restrict__ wr,
    const float* __restrict__ lng, const float* __restrict__ lnb,
    const float* __restrict__ b_pre, u16* __restrict__ s_out,
    int j0, int b0, int tid, char* smem) {
  float* hv = (float*)(smem + SM_HV);
  u16* lnH = (u16*)(smem + SM_LNH);
  u16* lnM = (u16*)(smem + SM_LNM);
  u16* lnL = (u16*)(smem + SM_LNL);
  float (*red)[16] = (float (*)[16])(smem + SM_RED);
  float* smean = (float*)(smem + SM_MEAN);
  float* srstd = (float*)(smem + SM_RSTD);
  bf16x8 p[12];
#pragma unroll
  for (int jj = 0; jj < 4; ++jj) {
    int c = tid + 256 * jj;
    int b = c >> 6, k0 = (c & 63) * 8;
    size_t base = (size_t)(b0 + b) * 512 + k0;
    p[jj * 3 + 0] = ldc16(hb + base);
    p[jj * 3 + 1] = ldc16(hb + APS + base);
    p[jj * 3 + 2] = ldc16(hb + 2 * APS + base);
  }
  vwait0_fence();   // rule #18: fence BEFORE any register-only use of p[]
#pragma unroll
  for (int jj = 0; jj < 4; ++jj) {
    int c = tid + 256 * jj;
    int b = c >> 6, k0 = (c & 63) * 8;
#pragma unroll
    for (int e = 0; e < 8; ++e)
      hv[b * 516 + k0 + e] = (bf2f((u16)p[jj * 3 + 2][e]) + bf2f((u16)p[jj * 3 + 1][e])) +
                             bf2f((u16)p[jj * 3 + 0][e]);
  }
  __syncthreads();
  int bl_ = tid >> 4, kc = tid & 15;
  {  // pass 1: mean
    float sm = 0.f;
    for (int kk = 0; kk < 32; ++kk) sm += hv[bl_ * 516 + kc * 32 + kk];
    red[bl_][kc] = sm;
  }
  __syncthreads();
  if (tid < 16) {
    float s1 = 0.f;
    for (int i = 0; i < 16; ++i) s1 += red[tid][i];
    smean[tid] = s1 * (1.f / 512.f);
  }
  __syncthreads();
  {  // pass 2: variance of deviations
    float m = smean[bl_], sq = 0.f;
    for (int kk = 0; kk < 32; ++kk) {
      float d = hv[bl_ * 516 + kc * 32 + kk] - m;
      sq += d * d;
    }
    red[bl_][kc] = sq;
  }
  __syncthreads();
  if (tid < 16) {
    float s2 = 0.f;
    for (int i = 0; i < 16; ++i) s2 += red[tid][i];
    srstd[tid] = 1.f / sqrtf(s2 * (1.f / 512.f) + 1e-5f);
  }
  __syncthreads();
  for (int i = tid; i < 16 * 512; i += 256) {
    int b = i >> 9, k = i & 511;
    float v = (hv[b * 516 + k] - smean[b]) * srstd[b] * lng[k] + lnb[k];
    splitbf3(v, &lnH[b * 520 + k], &lnM[b * 520 + k], &lnL[b * 520 + k]);
  }
  __syncthreads();
  int lane = tid & 63, w = tid >> 6, q = lane >> 4, r16 = lane & 15;
  const u16* aH = lnH + r16 * 520 + q * 8;
  const u16* aM = lnM + r16 * 520 + q * 8;
  const u16* aL = lnL + r16 * 520 + q * 8;
  f32x4 A0 = {0.f, 0.f, 0.f, 0.f}, A1 = {0.f, 0.f, 0.f, 0.f}, A2 = {0.f, 0.f, 0.f, 0.f};
#pragma unroll
  for (int kb = 0; kb < 16; ++kb) {
    bf16x8 ah = ldf(aH + kb * 32), am = ldf(aM + kb * 32), al = ldf(aL + kb * 32);
    bf16x8 bh = ldf(wr + kb * 32), bm = ldf(wr + PPS + kb * 32), bl = ldf(wr + 2 * PPS + kb * 32);
    MFMA6(ah, am, al, bh, bm, bl, A0, A1, A2);
  }
  int j = j0 + w * 16 + r16;
  float bp = b_pre[j];
#pragma unroll
  for (int r = 0; r < 4; ++r) {
    int b = q * 4 + r;
    float lnv = (hv[b * 516 + j] - smean[b]) * srstd[b] * lng[j] + lnb[j];  // exact fp32 recompute
    float pre = fmaxf(((A2[r] + A1[r]) + A0[r]) + bp, 0.f);
    float sval = pre + lnv;
    size_t sidx = (size_t)(b0 + b) * 512 + j;
    u16 sh, sm_, sl;
    splitbf3(sval, &sh, &sm_, &sl);
    stc2(s_out + sidx, sh);
    stc2(s_out + APS + sidx, sm_);
    stc2(s_out + 2 * APS + sidx, sl);
  }
}

// ---------------- fallback (round-3) tile functions ----------------

__device__ __forceinline__ void gate_tile(
    const u16* __restrict__ a0, const u16* __restrict__ a1,
    const u16* __restrict__ wr,
    const float* __restrict__ bias, int bias_stride,
    float* __restrict__ cstate, u16* __restrict__ hout,
    int b0, int h0, int tid, float (*gbuf)[16][16]) {
  int w = tid >> 6;
  int lane = tid & 63, q = lane >> 4, r16 = lane & 15;
  f32x4 A0 = {0.f, 0.f, 0.f, 0.f}, A1 = {0.f, 0.f, 0.f, 0.f}, A2 = {0.f, 0.f, 0.f, 0.f};
#pragma unroll
  for (int kb = 0; kb < 16; ++kb) {
    bf16x8 ah = ldf(a0 + kb * 32), am = ldf(a0 + APS + kb * 32), al = ldf(a0 + 2 * APS + kb * 32);
    bf16x8 bh = ldf(wr + kb * 32), bm = ldf(wr + WPS + kb * 32), bl = ldf(wr + 2 * WPS + kb * 32);
    MFMA6(ah, am, al, bh, bm, bl, A0, A1, A2);
  }
#pragma unroll
  for (int kb = 0; kb < 16; ++kb) {
    bf16x8 ah = ldf(a1 + kb * 32), am = ldf(a1 + APS + kb * 32), al = ldf(a1 + 2 * APS + kb * 32);
    bf16x8 bh = ldf(wr + 512 + kb * 32), bm = ldf(wr + WPS + 512 + kb * 32),
           bl = ldf(wr + 2 * WPS + 512 + kb * 32);
    MFMA6(ah, am, al, bh, bm, bl, A0, A1, A2);
  }
#pragma unroll
  for (int r = 0; r < 4; ++r)
    gbuf[w][q * 4 + r][r16] = (A2[r] + A1[r]) + A0[r];
  __syncthreads();
  int bl_ = tid >> 4, hl = tid & 15;
  int b = b0 + bl_, h = h0 + hl;
  const float* bb = bias + (size_t)b * bias_stride;
  float gi = gbuf[0][bl_][hl] + bb[h];
  float gf = gbuf[1][bl_][hl] + bb[512 + h];
  float gc = gbuf[2][bl_][hl] + bb[1024 + h];
  float go = gbuf[3][bl_][hl] + bb[1536 + h];
  int idx = b * 512 + h;
  float c = cstate[idx];
  float cn = sigm(gf) * c + sigm(gi) * tanhf(gc);
  cstate[idx] = cn;
  float hv_ = sigm(go) * tanhf(cn);
  splitbf3(hv_, &hout[idx], &hout[APS + idx], &hout[2 * APS + idx]);
  __syncthreads();
}

__device__ __forceinline__ void ys_tile(
    const u16* __restrict__ a, const u16* __restrict__ wr,
    const float* __restrict__ b_out, float* __restrict__ ys,
    int tout, int b0, int f0, int tid) {
  int lane = tid & 63, q = lane >> 4, r16 = lane & 15;
  f32x4 A0 = {0.f, 0.f, 0.f, 0.f}, A1 = {0.f, 0.f, 0.f, 0.f}, A2 = {0.f, 0.f, 0.f, 0.f};
#pragma unroll
  for (int kb = 0; kb < 16; ++kb) {
    bf16x8 ah = ldf(a + kb * 32), am = ldf(a + APS + kb * 32), al = ldf(a + 2 * APS + kb * 32);
    bf16x8 bh = ldf(wr + kb * 32), bm = ldf(wr + OPS + kb * 32), bl = ldf(wr + 2 * OPS + kb * 32);
    MFMA6(ah, am, al, bh, bm, bl, A0, A1, A2);
  }
  int fc = f0 + r16;
  float bo = b_out[fc];
#pragma unroll
  for (int r = 0; r < 4; ++r) {
    int b = b0 + q * 4 + r;
    ys[(size_t)b * (Ln * Fn) + (size_t)tout * Fn + fc] = ((A2[r] + A1[r]) + A0[r]) + bo;
  }
}

__device__ __forceinline__ void lnpre_tile(
    const u16* __restrict__ hb, const u16* __restrict__ wr,
    const float* __restrict__ lng, const float* __restrict__ lnb,
    const float* __restrict__ b_pre, u16* __restrict__ s_out,
    int j0, int b0, int tid, char* smem) {
  float* hv = (float*)(smem + SM_HV);
  u16* lnH = (u16*)(smem + SM_LNH);
  u16* lnM = (u16*)(smem + SM_LNM);
  u16* lnL = (u16*)(smem + SM_LNL);
  float (*red)[16] = (float (*)[16])(smem + SM_RED);
  float* smean = (float*)(smem + SM_MEAN);
  float* srstd = (float*)(smem + SM_RSTD);
  for (int i = tid; i < 16 * 512; i += 256) {
    int b = i >> 9, k = i & 511;
    size_t hidx = (size_t)(b0 + b) * 512 + k;
    hv[b * 516 + k] = (bf2f(hb[2 * APS + hidx]) + bf2f(hb[APS + hidx])) + bf2f(hb[hidx]);
  }
  __syncthreads();
  int bl_ = tid >> 4, kc = tid & 15;
  {
    float sm = 0.f;
    for (int kk = 0; kk < 32; ++kk) sm += hv[bl_ * 516 + kc * 32 + kk];
    red[bl_][kc] = sm;
  }
  __syncthreads();
  if (tid < 16) {
    float s1 = 0.f;
    for (int i = 0; i < 16; ++i) s1 += red[tid][i];
    smean[tid] = s1 * (1.f / 512.f);
  }
  __syncthreads();
  {
    float m = smean[bl_], sq = 0.f;
    for (int kk = 0; kk < 32; ++kk) {
      float d = hv[bl_ * 516 + kc * 32 + kk] - m;
      sq += d * d;
    }
    red[bl_][kc] = sq;
  }
  __syncthreads();
  if (tid < 16) {
    float s2 = 0.f;
    for (int i = 0; i < 16; ++i) s2 += red[tid][i];
    srstd[tid] = 1.f / sqrtf(s2 * (1.f / 512.f) + 1e-5f);
  }
  __syncthreads();
  for (int i = tid; i < 16 * 512; i += 256) {
    int b = i >> 9, k = i & 511;
    float v = (hv[b * 516 + k] - smean[b]) * srstd[b] * lng[k] + lnb[k];
    splitbf3(v, &lnH[b * 520 + k], &lnM[b * 520 + k], &lnL[b * 520 + k]);
  }
  __syncthreads();
  int lane = tid & 63, w = tid >> 6, q = lane >> 4, r16 = lane & 15;
  const u16* aH = lnH + r16 * 520 + q * 8;
  const u16* aM = lnM + r16 * 520 + q * 8;
  const u16* aL = lnL + r16 * 520 + q * 8;
  f32x4 A0 = {0.f, 0.f, 0.f, 0.f}, A1 = {0.f, 0.f, 0.f, 0.f}, A2 = {0.f, 0.f, 0.f, 0.f};
#pragma unroll
  for (int kb = 0; kb < 16; ++kb) {
    bf16x8 ah = ldf(aH + kb * 32), am = ldf(aM + kb * 32), al = ldf(aL + kb * 32);
    bf16x8 bh = ldf(wr + kb * 32), bm = ldf(wr + PPS + kb * 32), bl = ldf(wr + 2 * PPS + kb * 32);
    MFMA6(ah, am, al, bh, bm, bl, A0, A1, A2);
  }
  int j = j0 + w * 16 + r16;
  float bp = b_pre[j];
#pragma unroll
  for (int r = 0; r < 4; ++r) {
    int b = q * 4 + r;
    float lnv = (hv[b * 516 + j] - smean[b]) * srstd[b] * lng[j] + lnb[j];
    float pre = fmaxf(((A2[r] + A1[r]) + A0[r]) + bp, 0.f);
    float sval = pre + lnv;
    size_t sidx = (size_t)(b0 + b) * 512 + j;
    splitbf3(sval, &s_out[sidx], &s_out[APS + sidx], &s_out[2 * APS + sidx]);
  }
  __syncthreads();
}

// ---------------- prep kernels ----------------

__global__ void prep_hc0(const float* __restrict__ z,
                         const float* __restrict__ W_l2h, const float* __restrict__ b_l2h,
                         const float* __restrict__ W_l2c, const float* __restrict__ b_l2c,
                         u16* __restrict__ ha0, u16* __restrict__ hb0,
                         float* __restrict__ ca, float* __restrict__ cb) {
  int idx = blockIdx.x * 256 + threadIdx.x;  // 131072
  int b = idx & 127, j = idx >> 7;
  float ah = b_l2h[j], ac = b_l2c[j];
  for (int k = 0; k < 128; ++k) {
    float zv = z[b * 128 + k];
    ah += zv * W_l2h[j * 128 + k];
    ac += zv * W_l2c[j * 128 + k];
  }
  int flat = b * 1024 + j;
  if (flat < 65536) {
    splitbf3(ah, &ha0[flat], &ha0[APS + flat], &ha0[2 * APS + flat]);
    ca[flat] = ac;
  } else {
    flat -= 65536;
    splitbf3(ah, &hb0[flat], &hb0[APS + flat], &hb0[2 * APS + flat]);
    cb[flat] = ac;
  }
}

__global__ void prep_zp(const float* __restrict__ z, const float* __restrict__ W_zp,
                        const float* __restrict__ b_zp, float* __restrict__ zp) {
  int idx = blockIdx.x * 256 + threadIdx.x;  // 65536
  int b = idx & 127, h = idx >> 7;
  float a = b_zp[h];
  for (int k = 0; k < 128; ++k) a += z[b * 128 + k] * W_zp[h * 128 + k];
  zp[b * 512 + h] = a;
}

__global__ void prep_gz(const float* __restrict__ zp, const float* __restrict__ W_ih0,
                        const float* __restrict__ b_ih0, const float* __restrict__ b_hh0,
                        const float* __restrict__ b_out,
                        float* __restrict__ GZ0, float* __restrict__ GZ1) {
  int idx = blockIdx.x * 256 + threadIdx.x;  // 262144
  int b = idx & 127, g = idx >> 7;
  const float* wr = W_ih0 + (size_t)g * 640;
  float a = b_ih0[g] + b_hh0[g];
  for (int k = 0; k < 512; ++k) a += zp[b * 512 + k] * wr[128 + k];
  float co = 0.f;
  for (int f = 0; f < 128; ++f) co += b_out[f] * wr[f];
  GZ0[b * 2048 + g] = a;
  GZ1[b * 2048 + g] = a + co;
}

__global__ void prep_waf(const float* __restrict__ W_out, const float* __restrict__ W_ih0,
                         const float* __restrict__ W_hh0, u16* __restrict__ WAf) {
  int idx = blockIdx.x * 256 + threadIdx.x;  // 2097152
  int k = idx & 1023, g = idx >> 10;
  float v;
  if (k < 512) {
    v = 0.f;
    const float* wr = W_ih0 + (size_t)g * 640;
    for (int f = 0; f < 128; ++f) v += W_out[f * 512 + k] * wr[f];
  } else {
    v = W_hh0[(size_t)g * 512 + (k - 512)];
  }
  splitbf3(v, &WAf[idx], &WAf[WPS + idx], &WAf[2 * WPS + idx]);
}

__global__ void prep_wbf(const float* __restrict__ W_ih1, const float* __restrict__ W_hh1,
                         u16* __restrict__ WBf) {
  int idx = blockIdx.x * 256 + threadIdx.x;  // 2097152
  int k = idx & 1023, g = idx >> 10;
  float v = (k < 512) ? W_ih1[(size_t)g * 512 + k] : W_hh1[(size_t)g * 512 + (k - 512)];
  splitbf3(v, &WBf[idx], &WBf[WPS + idx], &WBf[2 * WPS + idx]);
}

__global__ void prep_misc(const float* __restrict__ W_pre, const float* __restrict__ W_out,
                          const float* __restrict__ b_ih1, const float* __restrict__ b_hh1,
                          u16* __restrict__ WPf, u16* __restrict__ WOf,
                          float* __restrict__ gb1, u16* __restrict__ s,
                          uint32* __restrict__ bar) {
  int idx = blockIdx.x * 256 + threadIdx.x;  // 530497 total
  if (idx < 262144) { splitbf3(W_pre[idx], &WPf[idx], &WPf[PPS + idx], &WPf[2 * PPS + idx]); return; }
  idx -= 262144;
  if (idx < 65536) { splitbf3(W_out[idx], &WOf[idx], &WOf[OPS + idx], &WOf[2 * OPS + idx]); return; }
  idx -= 65536;
  if (idx < 2048) { gb1[idx] = b_ih1[idx] + b_hh1[idx]; return; }
  idx -= 2048;
  if (idx < 196608) { s[idx] = 0; return; }  // all 3 planes of s1: dec(0)=0 via GZ0
  idx -= 196608;
  if (idx < BAR_WORDS) bar[idx] = 0;         // arrival slots + release word
}

// ---------------- persistent kernel ----------------

__global__ __launch_bounds__(256, 1) void loop_k(
    const u16* __restrict__ WAf, const u16* __restrict__ WBf,
    const u16* __restrict__ WPf, const u16* __restrict__ WOf,
    const float* __restrict__ GZ0, const float* __restrict__ GZ1,
    const float* __restrict__ gb1,
    const float* __restrict__ ca, const float* __restrict__ cb,
    u16* __restrict__ ha0, u16* __restrict__ ha1,
    u16* __restrict__ hb0, u16* __restrict__ hb1,
    u16* __restrict__ s0, u16* __restrict__ s1,
    const float* __restrict__ lng, const float* __restrict__ lnb,
    const float* __restrict__ b_pre, const float* __restrict__ b_out,
    float* __restrict__ ys, uint32* __restrict__ bar) {
  __shared__ __align__(16) u16 sAct[SACT_ELEMS];   // 99840 B, aliased by lnpre union
  __shared__ float gbuf[4][16][16];                // 4096 B, separate
  int tid = threadIdx.x;
  int lane = tid & 63, w = tid >> 6, q = lane >> 4, r16 = lane & 15;
  int blk = blockIdx.x;
  uint32* arr = bar;
  uint32* rel = bar + BAR_REL;

  int gg = blk & 31, bg = blk >> 5;
  int h0A = gg * 16, b0A = bg * 16;
  size_t wro = (size_t)(w * 512 + h0A + r16) * 1024 + q * 8;
  const u16* wrA = WAf + wro;
  const u16* wrB = WBf + wro;

  int jg = blk & 7, bgC = blk >> 3;
  int j0 = jg * 64, b0C = bgC * 16;
  const u16* wrP = WPf + (size_t)(j0 + w * 16 + r16) * 512 + q * 8;

  int ob = (blk - 64) & 15;
  int bgY = ob >> 1, fh = ob & 1;
  int b0Y = bgY * 16, f0 = fh * 64 + w * 16;
  const u16* wrO = WOf + (size_t)(f0 + r16) * 512 + q * 8;

  // cell state in registers: this thread owns (b0A+tid>>4, h0A+tid&15) forever
  int cidx = (b0A + (tid >> 4)) * 512 + h0A + (tid & 15);
  float cA = ca[cidx], cB = cb[cidx];

  uint32 ep = 0;
  for (int t = 0; t < Ln; ++t) {
    u16* sPrev = (t & 1) ? s0 : s1;   // written by phase C of t-1 (s1 zeroed for t=0)
    u16* sNext = (t & 1) ? s1 : s0;
    u16* haIn  = (t & 1) ? ha1 : ha0;
    u16* haOut = (t & 1) ? ha0 : ha1;
    u16* hbIn  = (t & 1) ? hb1 : hb0;
    u16* hbOut = (t & 1) ? hb0 : hb1;

    // phase A: cell0 (K=1024: s || ha)
    gate_tile_p(sPrev, haIn, wrA, t ? GZ1 : GZ0, 2048, cA, haOut, b0A, h0A, tid, sAct, gbuf);
    gbar(arr, rel, ++ep, blk);
    // phase B: cell1 (K=1024: ha' || hb)
    gate_tile_p(haOut, hbIn, wrB, gb1, 0, cB, hbOut, b0A, h0A, tid, sAct, gbuf);
    gbar(arr, rel, ++ep, blk);
    // phase C: lnpre (blocks 0..63) || ys[t-1] (blocks 64..79)
    if (blk < 64) {
      lnpre_tile_p(hbOut, wrP, lng, lnb, b_pre, sNext, j0, b0C, tid, (char*)sAct);
    } else if (blk < 80 && t > 0) {
      ys_tile_p(sPrev, wrO, b_out, ys, t - 1, b0Y, f0, tid, sAct);
    }
    gbar(arr, rel, ++ep, blk);
  }
  // epilogue: ys[L-1] from final s (t=255 wrote s1)
  if (blk >= 64 && blk < 80) {
    ys_tile_p(s1, wrO, b_out, ys, Ln - 1, b0Y, f0, tid, sAct);
  }
}

// ---------------- fallback per-step kernels (round-3 path) ----------------

__global__ void cell_k(const u16* __restrict__ x0, const u16* __restrict__ x1,
                       const u16* __restrict__ Wf,
                       const float* __restrict__ bias, int bias_stride,
                       float* __restrict__ cstate, u16* __restrict__ hout,
                       int n_gate_blocks,
                       const u16* sv, const u16* __restrict__ WOf,
                       const float* __restrict__ b_out, float* __restrict__ ys, int t) {
  __shared__ float gbuf[4][16][16];
  int tid = threadIdx.x;
  int lane = tid & 63, w = tid >> 6, q = lane >> 4, r16 = lane & 15;
  int blk = blockIdx.x;
  if (blk < n_gate_blocks) {
    int gg = blk & 31, bg = blk >> 5;
    int h0 = gg * 16, b0 = bg * 16;
    const u16* wr = Wf + (size_t)(w * 512 + h0 + r16) * 1024 + q * 8;
    size_t aoff = (size_t)(b0 + r16) * 512 + q * 8;
    gate_tile(x0 + aoff, x1 + aoff, wr, bias, bias_stride, cstate, hout, b0, h0, tid, gbuf);
  } else {
    if (t < 1) return;
    int ob = blk - n_gate_blocks;
    int bg = ob >> 1, fh = ob & 1;
    int b0 = bg * 16, f0 = fh * 64 + w * 16;
    const u16* wr = WOf + (size_t)(f0 + r16) * 512 + q * 8;
    size_t aoff = (size_t)(b0 + r16) * 512 + q * 8;
    ys_tile(sv + aoff, wr, b_out, ys, t - 1, b0, f0, tid);
  }
}

__global__ void lnpre_k(const u16* __restrict__ hb, const u16* __restrict__ WPf,
                        const float* __restrict__ lng, const float* __restrict__ lnb,
                        const float* __restrict__ b_pre, u16* __restrict__ s_out) {
  __shared__ __align__(16) char smem[SMEM_BYTES];
  int tid = threadIdx.x;
  int lane = tid & 63, w = tid >> 6, q = lane >> 4, r16 = lane & 15;
  int jg = blockIdx.x & 7, bg = blockIdx.x >> 3;
  int j0 = jg * 64, b0 = bg * 16;
  const u16* wr = WPf + (size_t)(j0 + w * 16 + r16) * 512 + q * 8;
  lnpre_tile(hb, wr, lng, lnb, b_pre, s_out, j0, b0, tid, smem);
}

// ---------------- host ----------------

extern "C" void kernel_launch(void* const* d_in, const int* in_sizes, int n_in,
                              void* d_out, int out_size, void* d_ws, size_t ws_size,
                              hipStream_t stream) {
  const float* z     = (const float*)d_in[0];
  const float* W_l2h = (const float*)d_in[1];
  const float* b_l2h = (const float*)d_in[2];
  const float* W_l2c = (const float*)d_in[3];
  const float* b_l2c = (const float*)d_in[4];
  const float* W_zp  = (const float*)d_in[5];
  const float* b_zp  = (const float*)d_in[6];
  const float* W_ih0 = (const float*)d_in[7];
  const float* W_hh0 = (const float*)d_in[8];
  const float* b_ih0 = (const float*)d_in[9];
  const float* b_hh0 = (const float*)d_in[10];
  const float* W_ih1 = (const float*)d_in[11];
  const float* W_hh1 = (const float*)d_in[12];
  const float* b_ih1 = (const float*)d_in[13];
  const float* b_hh1 = (const float*)d_in[14];
  const float* ln_g  = (const float*)d_in[15];
  const float* ln_b  = (const float*)d_in[16];
  const float* W_pre = (const float*)d_in[17];
  const float* b_pre = (const float*)d_in[18];
  const float* W_out = (const float*)d_in[19];
  const float* b_out = (const float*)d_in[20];
  float* out = (float*)d_out;
  char* ws = (char*)d_ws;

  size_t off = 0;
  auto alloc = [&](size_t bytes) { void* p = ws + off; off += bytes; return p; };
  u16*   WAf  = (u16*)alloc(12582912);   // 3 planes x 2048x1024 bf16
  u16*   WBf  = (u16*)alloc(12582912);
  u16*   WPf  = (u16*)alloc(1572864);    // 3 x 512x512
  u16*   WOf  = (u16*)alloc(393216);     // 3 x 128x512
  float* GZ0  = (float*)alloc(1048576);
  float* GZ1  = (float*)alloc(1048576);
  float* gb1  = (float*)alloc(8192);
  float* zp   = (float*)alloc(262144);
  u16*   ha[2], *hbuf[2], *sb[2];
  ha[0]   = (u16*)alloc(393216);         // 3 planes x 128x512
  ha[1]   = (u16*)alloc(393216);
  hbuf[0] = (u16*)alloc(393216);
  hbuf[1] = (u16*)alloc(393216);
  float* ca   = (float*)alloc(262144);
  float* cb   = (float*)alloc(262144);
  sb[0]   = (u16*)alloc(393216);
  sb[1]   = (u16*)alloc(393216);
  uint32* bar = (uint32*)alloc(32768);   // arrival slots (16KB) + release word

  prep_hc0<<<512, 256, 0, stream>>>(z, W_l2h, b_l2h, W_l2c, b_l2c, ha[0], hbuf[0], ca, cb);
  prep_zp<<<256, 256, 0, stream>>>(z, W_zp, b_zp, zp);
  prep_gz<<<1024, 256, 0, stream>>>(zp, W_ih0, b_ih0, b_hh0, b_out, GZ0, GZ1);
  prep_waf<<<8192, 256, 0, stream>>>(W_out, W_ih0, W_hh0, WAf);
  prep_wbf<<<8192, 256, 0, stream>>>(W_ih1, W_hh1, WBf);
  prep_misc<<<2073, 256, 0, stream>>>(W_pre, W_out, b_ih1, b_hh1, WPf, WOf, gb1, sb[1], bar);

  static int coop_supported = -1;
  if (coop_supported < 0) {
    int dev = 0;
    (void)hipGetDevice(&dev);
    int v = 0;
    (void)hipDeviceGetAttribute(&v, hipDeviceAttributeCooperativeLaunch, dev);
    coop_supported = v;
  }

  bool did_coop = false;
  if (coop_supported) {
    void* kargs[] = {
        (void*)&WAf, (void*)&WBf, (void*)&WPf, (void*)&WOf,
        (void*)&GZ0, (void*)&GZ1, (void*)&gb1, (void*)&ca, (void*)&cb,
        (void*)&ha[0], (void*)&ha[1], (void*)&hbuf[0], (void*)&hbuf[1],
        (void*)&sb[0], (void*)&sb[1],
        (void*)&ln_g, (void*)&ln_b, (void*)&b_pre, (void*)&b_out, (void*)&out,
        (void*)&bar};
    hipError_t err = hipLaunchCooperativeKernel((const void*)loop_k, dim3(256), dim3(256),
                                                kargs, 0, stream);
    did_coop = (err == hipSuccess);
  }

  if (!did_coop) {
    // fallback: per-step launches (round-3 structure)
    for (int t = 0; t < Ln; ++t) {
      u16* sPrev = (t & 1) ? sb[0] : sb[1];
      u16* sNext = (t & 1) ? sb[1] : sb[0];
      u16* haIn = ha[t & 1];
      u16* haOut = ha[(t + 1) & 1];
      u16* hbIn = hbuf[t & 1];
      u16* hbOut = hbuf[(t + 1) & 1];
      cell_k<<<272, 256, 0, stream>>>(sPrev, haIn, WAf, t ? GZ1 : GZ0, 2048,
                                      ca, haOut, 256, sPrev, WOf, b_out, out, t);
      cell_k<<<256, 256, 0, stream>>>(haOut, hbIn, WBf, gb1, 0,
                                      cb, hbOut, 256, sPrev, WOf, b_out, out, 0);
      lnpre_k<<<64, 256, 0, stream>>>(hbOut, WPf, ln_g, ln_b, b_pre, sNext);
    }
    cell_k<<<16, 256, 0, stream>>>(sb[1], ha[0], WAf, GZ1, 2048, ca, ha[1],
                                   0, sb[1], WOf, b_out, out, Ln);
  }
}